// Round 9
// baseline (205.054 us; speedup 1.0000x reference)
//
#include <hip/hip_runtime.h>
#include <math.h>

// DynamicAttention1 — round 9: fuse the tail; exploit bias cancellation.
// R8 was neutral -> atomics exonerated. Accounting: ~56us fixed harness window
// + ~77us kernels/gaps, with ~40us attributable to 4 dependent-launch gaps
// (~10us each). Changes:
//   * bs cancels EXACTLY (scores: difference q*(sk-tk); ctx: sum(w)=1) ->
//     keys bias-init dropped; keys zeroed by hipMemsetAsync (split-K base)
//   * scgemm+softmax+ctx+out_right fused into k_attn (128 blocks of 8 l-rows):
//     scores MFMA with A/B straight from global (keys cvt bf16 in-register),
//     in-block softmax, ctx VALU, ctx->LDS bf16, out_right MFMA + atomics
//   * sc / aout buffers and 2 kernels (2 gaps) eliminated
// Pipeline: memset(keys) -> prep -> stageB(keys x2 + q + out_left) -> attn

typedef __attribute__((ext_vector_type(8))) short s16x8;
typedef __attribute__((ext_vector_type(4))) float f32x4;

__device__ __forceinline__ unsigned short f2bf(float f) {
    unsigned int u = __float_as_uint(f);
    return (unsigned short)((u + 0x7fffu + ((u >> 16) & 1u)) >> 16);  // RNE
}

__device__ __forceinline__ s16x8 cvt8(const float* p) {
    float4 u = *(const float4*)p, w = *(const float4*)(p + 4);
    s16x8 o;
    o[0] = (short)f2bf(u.x); o[1] = (short)f2bf(u.y);
    o[2] = (short)f2bf(u.z); o[3] = (short)f2bf(u.w);
    o[4] = (short)f2bf(w.x); o[5] = (short)f2bf(w.y);
    o[6] = (short)f2bf(w.z); o[7] = (short)f2bf(w.w);
    return o;
}

// ---------------- prep: casts + weight transposes ---------------------------
__global__ __launch_bounds__(256) void k_prep(
    const float* __restrict__ query, const float* __restrict__ src,
    const float* __restrict__ trg, const float* __restrict__ Wq,
    const float* __restrict__ Ws, const float* __restrict__ Wo,
    unsigned short* __restrict__ qbf, unsigned short* __restrict__ abf,
    unsigned short* __restrict__ WqT, unsigned short* __restrict__ WsT,
    unsigned short* __restrict__ WoT) {
    __shared__ float tile[32][33];
    const int bid = blockIdx.x, t = threadIdx.x;

    if (bid < 3712) {                       // activation casts (float4 groups)
        const int idx = bid * 256 + t;
        if (idx < 131072) {
            float4 v = *(const float4*)(query + (size_t)idx * 4);
            *(ushort4*)(qbf + (size_t)idx * 4) =
                make_ushort4(f2bf(v.x), f2bf(v.y), f2bf(v.z), f2bf(v.w));
        } else if (idx < 540672) {
            const int i = idx - 131072;
            float4 v = *(const float4*)(src + (size_t)i * 4);
            *(ushort4*)(abf + (size_t)i * 4) =
                make_ushort4(f2bf(v.x), f2bf(v.y), f2bf(v.z), f2bf(v.w));
        } else {
            const int i = idx - 540672;
            float4 v = *(const float4*)(trg + (size_t)i * 4);
            *(ushort4*)(abf + 1638400 + (size_t)i * 4) =
                make_ushort4(f2bf(v.x), f2bf(v.y), f2bf(v.z), f2bf(v.w));
        }
    } else {                                // weight transpose-cast, 32x32 tiles
        const int id = bid - 3712;
        const float* W; unsigned short* O; int K, tk, tn;
        if (id < 256)       { W = Wq; O = WqT; K = 512;  tk = id >> 4;          tn = id & 15; }
        else if (id < 1280) { W = Ws; O = WsT; K = 2048; tk = (id - 256) >> 4;  tn = (id - 256) & 15; }
        else                { W = Wo; O = WoT; K = 1024; tk = (id - 1280) >> 4; tn = (id - 1280) & 15; }
        const int row = t >> 3, c4 = (t & 7) * 4;
        float4 v = *(const float4*)(W + (size_t)(tk * 32 + row) * 512 + tn * 32 + c4);
        tile[row][c4 + 0] = v.x; tile[row][c4 + 1] = v.y;
        tile[row][c4 + 2] = v.z; tile[row][c4 + 3] = v.w;
        __syncthreads();
        ushort4 o = make_ushort4(f2bf(tile[c4 + 0][row]), f2bf(tile[c4 + 1][row]),
                                 f2bf(tile[c4 + 2][row]), f2bf(tile[c4 + 3][row]));
        *(ushort4*)(O + (size_t)(tn * 32 + row) * K + tk * 32 + c4) = o;
    }
}

// ---------------- MFMA GEMM bodies (register-prefetch pipelined) ------------
// 64x64 tile, 4 waves 2x2; split-K partial accumulated via fp32 atomics.
__device__ __forceinline__ void gemm64_atomic(
    const unsigned short* __restrict__ A, const unsigned short* __restrict__ BT,
    float* __restrict__ C, int m0, int n0, int K, int N, int kbase, int kiters,
    unsigned short* As, unsigned short* Bs) {
    const int t = threadIdx.x;
    const int lane = t & 63, wid = t >> 6;
    const int wm = (wid & 1) * 32, wn = (wid >> 1) * 32;
    const int lr = lane & 15, lq = lane >> 4;
    const int r = t >> 3, c8 = (t & 7) * 8;

    s16x8 ra0, ra1, rb0, rb1;
#define LD64(kt)                                                           \
    ra0 = *(const s16x8*)(A  + (size_t)(m0 + r)      * K + (kt) + c8);     \
    ra1 = *(const s16x8*)(A  + (size_t)(m0 + r + 32) * K + (kt) + c8);     \
    rb0 = *(const s16x8*)(BT + (size_t)(n0 + r)      * K + (kt) + c8);     \
    rb1 = *(const s16x8*)(BT + (size_t)(n0 + r + 32) * K + (kt) + c8);

    f32x4 acc[2][2] = {};
    LD64(kbase);
    for (int it = 0; it < kiters; it++) {
        __syncthreads();
        *(s16x8*)&As[r * 72 + c8]        = ra0;
        *(s16x8*)&As[(r + 32) * 72 + c8] = ra1;
        *(s16x8*)&Bs[r * 72 + c8]        = rb0;
        *(s16x8*)&Bs[(r + 32) * 72 + c8] = rb1;
        __syncthreads();
        if (it + 1 < kiters) { LD64(kbase + (it + 1) * 64); }  // prefetch
#pragma unroll
        for (int s = 0; s < 2; s++) {
            s16x8 a0 = *(const s16x8*)&As[(wm + lr) * 72      + s * 32 + lq * 8];
            s16x8 a1 = *(const s16x8*)&As[(wm + 16 + lr) * 72 + s * 32 + lq * 8];
            s16x8 b0 = *(const s16x8*)&Bs[(wn + lr) * 72      + s * 32 + lq * 8];
            s16x8 b1 = *(const s16x8*)&Bs[(wn + 16 + lr) * 72 + s * 32 + lq * 8];
            acc[0][0] = __builtin_amdgcn_mfma_f32_16x16x32_bf16(a0, b0, acc[0][0], 0, 0, 0);
            acc[0][1] = __builtin_amdgcn_mfma_f32_16x16x32_bf16(a0, b1, acc[0][1], 0, 0, 0);
            acc[1][0] = __builtin_amdgcn_mfma_f32_16x16x32_bf16(a1, b0, acc[1][0], 0, 0, 0);
            acc[1][1] = __builtin_amdgcn_mfma_f32_16x16x32_bf16(a1, b1, acc[1][1], 0, 0, 0);
        }
    }
#undef LD64
#pragma unroll
    for (int i = 0; i < 2; i++)
#pragma unroll
        for (int j = 0; j < 2; j++) {
            const int col = n0 + wn + j * 16 + lr;      // C/D: col=lane&15
            const int row = m0 + wm + i * 16 + lq * 4;  //      row=quad*4+reg
#pragma unroll
            for (int rr = 0; rr < 4; rr++)
                unsafeAtomicAdd(&C[(size_t)(row + rr) * N + col], acc[i][j][rr]);
        }
}

// 32x64 tile, 4 waves. MODE 0: fp32+bias direct, 2: bf16+bias direct.
template <int MODE>
__device__ __forceinline__ void gemm32(
    const unsigned short* __restrict__ A, const unsigned short* __restrict__ BT,
    const float* __restrict__ bias, void* __restrict__ Cv,
    int m0, int n0, int KA, int KB, int N, int kbase, int kiters,
    unsigned short* As, unsigned short* Bs) {
    const int t = threadIdx.x;
    const int lane = t & 63, wid = t >> 6;
    const int wm = (wid & 1) * 16, wn = (wid >> 1) * 32;
    const int lr = lane & 15, lq = lane >> 4;
    const int r = t >> 3, c8 = (t & 7) * 8;

    s16x8 ra, rb0, rb1;
#define LD32(kt)                                                            \
    ra  = *(const s16x8*)(A  + (size_t)(m0 + r)      * KA + (kt) + c8);     \
    rb0 = *(const s16x8*)(BT + (size_t)(n0 + r)      * KB + (kt) + c8);     \
    rb1 = *(const s16x8*)(BT + (size_t)(n0 + r + 32) * KB + (kt) + c8);

    f32x4 acc[2] = {};
    LD32(kbase);
    for (int it = 0; it < kiters; it++) {
        __syncthreads();
        *(s16x8*)&As[r * 72 + c8]        = ra;
        *(s16x8*)&Bs[r * 72 + c8]        = rb0;
        *(s16x8*)&Bs[(r + 32) * 72 + c8] = rb1;
        __syncthreads();
        if (it + 1 < kiters) { LD32(kbase + (it + 1) * 64); }  // prefetch
#pragma unroll
        for (int s = 0; s < 2; s++) {
            s16x8 a0 = *(const s16x8*)&As[(wm + lr) * 72      + s * 32 + lq * 8];
            s16x8 b0 = *(const s16x8*)&Bs[(wn + lr) * 72      + s * 32 + lq * 8];
            s16x8 b1 = *(const s16x8*)&Bs[(wn + 16 + lr) * 72 + s * 32 + lq * 8];
            acc[0] = __builtin_amdgcn_mfma_f32_16x16x32_bf16(a0, b0, acc[0], 0, 0, 0);
            acc[1] = __builtin_amdgcn_mfma_f32_16x16x32_bf16(a0, b1, acc[1], 0, 0, 0);
        }
    }
#undef LD32
#pragma unroll
    for (int j = 0; j < 2; j++) {
        const int col = n0 + wn + j * 16 + lr;
        const int row = m0 + wm + lq * 4;
        const float bv = bias[col];
        if (MODE == 0) {
            float* C = (float*)Cv;
#pragma unroll
            for (int rr = 0; rr < 4; rr++)
                C[(size_t)(row + rr) * N + col] = acc[j][rr] + bv;
        } else {
            unsigned short* C = (unsigned short*)Cv;
#pragma unroll
            for (int rr = 0; rr < 4; rr++)
                C[(size_t)(row + rr) * N + col] = f2bf(acc[j][rr] + bv);
        }
    }
}

// ---------------- stage B: keys splitKx2 + q GEMM + out_left ----------------
// [0,400): keys (64x64, splitK x2, atomics onto zeroed keys; NO bias — bs
//          cancels exactly in scores AND ctx since softmax weights sum to 1)
// [400,656): qh = query @ Wq + bq -> bf16
// [656,912): out = query @ WoTop + bo -> fp32 direct
__global__ __launch_bounds__(256) void k_stageB(
    const unsigned short* __restrict__ qbf, const unsigned short* __restrict__ abf,
    const unsigned short* __restrict__ WqT, const unsigned short* __restrict__ WsT,
    const unsigned short* __restrict__ WoT, const float* __restrict__ bq,
    const float* __restrict__ bo, unsigned short* __restrict__ qh,
    float* __restrict__ keys, float* __restrict__ out) {
    __shared__ __align__(16) unsigned short As[64 * 72];
    __shared__ __align__(16) unsigned short Bs[64 * 72];
    const int bid = blockIdx.x;
    if (bid < 400) {
        const int c = bid / 200, rem = bid % 200;
        const int mt = rem >> 3, nt = rem & 7;
        gemm64_atomic(abf, WsT, keys, mt * 64, nt * 64, 2048, 512,
                      c * 1024, 16, As, Bs);
    } else if (bid < 656) {
        const int r = bid - 400;
        const int mt = r >> 3, nt = r & 7;
        gemm32<2>(qbf, WqT, bq, qh, mt * 32, nt * 64, 512, 512, 512,
                  0, 8, As, Bs);
    } else {
        const int r = bid - 656;
        const int mt = r >> 3, nt = r & 7;
        gemm32<0>(qbf, WoT, bo, out, mt * 32, nt * 64, 512, 1024, 512,
                  0, 8, As, Bs);
    }
}

// ---------------- attn: scores MFMA + softmax + ctx VALU + out_right --------
// 128 blocks = (16 l-tiles of 8 rows) x (8 b). Per block:
//  A) S[16][208] = qh @ keysT (MFMA, A/B direct from global, keys cvt bf16;
//     scale +-1/32 applied at write; rows 8..15 / cols 200..207 garbage-ok)
//  B) masked softmax rows 0..7 -> wT[st][l] fp32
//  C) ctx VALU (keys chunks staged in LDS) -> ctxbuf[l][n] bf16 (/sqrt2)
//  D) out[m0+l][:] += ctxbuf @ WoBot (MFMA, B direct from global, atomics)
__global__ __launch_bounds__(256) void k_attn(
    const unsigned short* __restrict__ qh,   // [1040][512] (rows>=1024 garbage)
    const float* __restrict__ keys,          // [1600][512] unbiased projections
    const unsigned short* __restrict__ wot,  // [512][1024]
    float* __restrict__ out) {               // [1024][512], has out_left+bo
    __shared__ float Sbuf[16][216];              // 13.8 KB
    __shared__ float wT[200][9];                 //  7.2 KB
    __shared__ float Bs2[40][132];               // 21.1 KB
    __shared__ unsigned short ctxbuf[16][528];   // 16.9 KB (rows 8..15 garbage)

    const int t = threadIdx.x, lane = t & 63, wid = t >> 6;
    const int b = blockIdx.y, lt = blockIdx.x;
    const int m0 = b * 128 + lt * 8;
    const int lr = lane & 15, lq = lane >> 4;

    // ---- A: scores ----
    for (int tile = wid; tile < 13; tile += 4) {
        const int st = tile * 16 + lr;
        const int kr = (st < 100) ? (b * 100 + st)
                     : (st < 200) ? (800 + b * 100 + (st - 100)) : 1599;
        f32x4 acc = {};
        for (int ks = 0; ks < 16; ks++) {
            s16x8 a = *(const s16x8*)(qh + (size_t)(m0 + lr) * 512 + ks * 32 + lq * 8);
            s16x8 bf = cvt8(keys + (size_t)kr * 512 + ks * 32 + lq * 8);
            acc = __builtin_amdgcn_mfma_f32_16x16x32_bf16(a, bf, acc, 0, 0, 0);
        }
        const float scale = (st < 100) ? (1.0f / 32.0f) : (-1.0f / 32.0f);
#pragma unroll
        for (int rr = 0; rr < 4; rr++)
            Sbuf[lq * 4 + rr][st] = acc[rr] * scale;
    }
    __syncthreads();

    // ---- B: masked softmax, one row per half-wave (8 rows) ----
    {
        const int row = t >> 5, sl = t & 31;
        float v[7], e[7];
        float mS = -1e30f, mT = -1e30f;
#pragma unroll
        for (int j = 0; j < 7; j++) {
            const int c = sl + 32 * j;
            v[j] = (c < 200) ? Sbuf[row][c] : -1e30f;
            if (c < 100) mS = fmaxf(mS, v[j]);
            else if (c < 200) mT = fmaxf(mT, v[j]);
        }
#pragma unroll
        for (int off = 16; off > 0; off >>= 1) {
            mS = fmaxf(mS, __shfl_xor(mS, off));
            mT = fmaxf(mT, __shfl_xor(mT, off));
        }
        float sS = 0.f, sT = 0.f;
#pragma unroll
        for (int j = 0; j < 7; j++) {
            const int c = sl + 32 * j;
            if (c < 100)      { e[j] = __expf(v[j] - mS); sS += e[j]; }
            else if (c < 200) { e[j] = __expf(v[j] - mT); sT += e[j]; }
            else e[j] = 0.f;
        }
#pragma unroll
        for (int off = 16; off > 0; off >>= 1) {
            sS += __shfl_xor(sS, off);
            sT += __shfl_xor(sT, off);
        }
        const float iS = 1.f / sS, iT = 1.f / sT;
#pragma unroll
        for (int j = 0; j < 7; j++) {
            const int c = sl + 32 * j;
            if (c < 100)      wT[c][row] = e[j] * iS;
            else if (c < 200) wT[c][row] = e[j] * iT;
        }
    }
    __syncthreads();

    // ---- C: ctx VALU -> ctxbuf bf16 ----
    {
        const int ty = t >> 5;          // l 0..7
        const int tx = t & 31;          // n4 within 128-col chunk
        const float s2 = 0.70710678118654752f;
        for (int nc = 0; nc < 4; nc++) {
            float a4[4] = {};
            for (int c5 = 0; c5 < 5; c5++) {
                __syncthreads();
#pragma unroll
                for (int e = 0; e < 20; e++) {
                    const int idx = t + e * 256;
                    const int k = idx >> 7, n = idx & 127;
                    const int kk = c5 * 40 + k;
                    Bs2[k][n] = (kk < 100)
                        ?  keys[(size_t)(b * 100 + kk) * 512 + nc * 128 + n]
                        : -keys[(size_t)(800 + b * 100 + (kk - 100)) * 512 + nc * 128 + n];
                }
                __syncthreads();
#pragma unroll 8
                for (int k = 0; k < 40; k++) {
                    const float ar = wT[c5 * 40 + k][ty];
                    float br[4];
                    *(float4*)br = *(const float4*)&Bs2[k][tx * 4];
#pragma unroll
                    for (int j = 0; j < 4; j++) a4[j] = fmaf(ar, br[j], a4[j]);
                }
            }
            ushort4 o = make_ushort4(f2bf(a4[0] * s2), f2bf(a4[1] * s2),
                                     f2bf(a4[2] * s2), f2bf(a4[3] * s2));
            *(ushort4*)&ctxbuf[ty][nc * 128 + tx * 4] = o;
        }
    }
    __syncthreads();

    // ---- D: out_right MFMA, atomics into out ----
    for (int nt = wid; nt < 32; nt += 4) {
        const int col = nt * 16 + lr;
        f32x4 acc = {};
        for (int ks = 0; ks < 16; ks++) {
            s16x8 a = *(const s16x8*)&ctxbuf[lr][ks * 32 + lq * 8];
            s16x8 bf = *(const s16x8*)(wot + (size_t)col * 1024 + 512 + ks * 32 + lq * 8);
            acc = __builtin_amdgcn_mfma_f32_16x16x32_bf16(a, bf, acc, 0, 0, 0);
        }
        if (lq < 2) {                       // rows lq*4+rr in [0,8) valid
#pragma unroll
            for (int rr = 0; rr < 4; rr++)
                unsafeAtomicAdd(&out[(size_t)(m0 + lq * 4 + rr) * 512 + col],
                                acc[rr]);
        }
    }
}

// ---------------- launch ----------------------------------------------------

extern "C" void kernel_launch(void* const* d_in, const int* in_sizes, int n_in,
                              void* d_out, int out_size, void* d_ws, size_t ws_size,
                              hipStream_t stream) {
    const float* query = (const float*)d_in[0];
    const float* src   = (const float*)d_in[1];
    const float* trg   = (const float*)d_in[2];
    const float* Wq    = (const float*)d_in[3];
    const float* bq    = (const float*)d_in[4];
    const float* Ws    = (const float*)d_in[5];
    const float* Wo    = (const float*)d_in[7];
    const float* bo    = (const float*)d_in[8];
    float* out = (float*)d_out;

    float* keys = (float*)d_ws;               // 1600*512 fp32
    unsigned short* qbf = (unsigned short*)(keys + 819200);  // 1024x512
    unsigned short* qh  = qbf + 524288;       // 1040x512 (16 pad rows)
    unsigned short* abf = qh  + 532480;       // [src;trg] 1600x2048
    unsigned short* wqt = abf + 3276800;      // WqT 512x512
    unsigned short* wst = wqt + 262144;       // WsT 512x2048
    unsigned short* wot = wst + 1048576;      // WoT 512x1024

    hipMemsetAsync(keys, 0, 819200 * sizeof(float), stream);
    k_prep<<<5504, 256, 0, stream>>>(query, src, trg, Wq, Ws, Wo,
                                     qbf, abf, wqt, wst, wot);
    k_stageB<<<912, 256, 0, stream>>>(qbf, abf, wqt, wst, wot, bq, bo,
                                      qh, keys, out);
    k_attn<<<dim3(16, 8), 256, 0, stream>>>(qh, keys, wot, out);
}

// Round 10
// 151.593 us; speedup vs baseline: 1.3527x; 1.3527x over previous
//
#include <hip/hip_runtime.h>
#include <math.h>

// DynamicAttention1 — round 10: R8 structure + k_out folded into k_ctx.
// R9 lesson: few-block fused kernels die of occupancy (k_attn: 128 blocks,
// 59KB LDS, Occ 5.6%, 104us). Keep the 512-block ctx shape and fold the
// out-right GEMM into it as a rank-32 atomic update per block:
//   * ctx tile [32l][32n] -> LDS bf16 -> 16 K=32 MFMAs vs wot slice ->
//     atomicAdd into out (stageB pre-filled query@WoTop+bo)
//   * aout buffer + k_out kernel + 1 gap eliminated (kernels 5 -> 4)
//   * prep/stageB/memset verbatim from R9 (proven); scgemm verbatim from R8
// Pipeline: memset(keys) -> prep -> stageB(keys x2 + qh + out_left) ->
//           scgemm -> ctxout

typedef __attribute__((ext_vector_type(8))) short s16x8;
typedef __attribute__((ext_vector_type(4))) float f32x4;

__device__ __forceinline__ unsigned short f2bf(float f) {
    unsigned int u = __float_as_uint(f);
    return (unsigned short)((u + 0x7fffu + ((u >> 16) & 1u)) >> 16);  // RNE
}

__device__ __forceinline__ s16x8 cvt8(const float* p) {
    float4 u = *(const float4*)p, w = *(const float4*)(p + 4);
    s16x8 o;
    o[0] = (short)f2bf(u.x); o[1] = (short)f2bf(u.y);
    o[2] = (short)f2bf(u.z); o[3] = (short)f2bf(u.w);
    o[4] = (short)f2bf(w.x); o[5] = (short)f2bf(w.y);
    o[6] = (short)f2bf(w.z); o[7] = (short)f2bf(w.w);
    return o;
}

// ---------------- prep: casts + weight transposes ---------------------------
__global__ __launch_bounds__(256) void k_prep(
    const float* __restrict__ query, const float* __restrict__ src,
    const float* __restrict__ trg, const float* __restrict__ Wq,
    const float* __restrict__ Ws, const float* __restrict__ Wo,
    unsigned short* __restrict__ qbf, unsigned short* __restrict__ abf,
    unsigned short* __restrict__ WqT, unsigned short* __restrict__ WsT,
    unsigned short* __restrict__ WoT) {
    __shared__ float tile[32][33];
    const int bid = blockIdx.x, t = threadIdx.x;

    if (bid < 3712) {                       // activation casts (float4 groups)
        const int idx = bid * 256 + t;
        if (idx < 131072) {
            float4 v = *(const float4*)(query + (size_t)idx * 4);
            *(ushort4*)(qbf + (size_t)idx * 4) =
                make_ushort4(f2bf(v.x), f2bf(v.y), f2bf(v.z), f2bf(v.w));
        } else if (idx < 540672) {
            const int i = idx - 131072;
            float4 v = *(const float4*)(src + (size_t)i * 4);
            *(ushort4*)(abf + (size_t)i * 4) =
                make_ushort4(f2bf(v.x), f2bf(v.y), f2bf(v.z), f2bf(v.w));
        } else {
            const int i = idx - 540672;
            float4 v = *(const float4*)(trg + (size_t)i * 4);
            *(ushort4*)(abf + 1638400 + (size_t)i * 4) =
                make_ushort4(f2bf(v.x), f2bf(v.y), f2bf(v.z), f2bf(v.w));
        }
    } else {                                // weight transpose-cast, 32x32 tiles
        const int id = bid - 3712;
        const float* W; unsigned short* O; int K, tk, tn;
        if (id < 256)       { W = Wq; O = WqT; K = 512;  tk = id >> 4;          tn = id & 15; }
        else if (id < 1280) { W = Ws; O = WsT; K = 2048; tk = (id - 256) >> 4;  tn = (id - 256) & 15; }
        else                { W = Wo; O = WoT; K = 1024; tk = (id - 1280) >> 4; tn = (id - 1280) & 15; }
        const int row = t >> 3, c4 = (t & 7) * 4;
        float4 v = *(const float4*)(W + (size_t)(tk * 32 + row) * 512 + tn * 32 + c4);
        tile[row][c4 + 0] = v.x; tile[row][c4 + 1] = v.y;
        tile[row][c4 + 2] = v.z; tile[row][c4 + 3] = v.w;
        __syncthreads();
        ushort4 o = make_ushort4(f2bf(tile[c4 + 0][row]), f2bf(tile[c4 + 1][row]),
                                 f2bf(tile[c4 + 2][row]), f2bf(tile[c4 + 3][row]));
        *(ushort4*)(O + (size_t)(tn * 32 + row) * K + tk * 32 + c4) = o;
    }
}

// ---------------- MFMA GEMM bodies (register-prefetch pipelined) ------------
// 64x64 tile, 4 waves 2x2; split-K partial accumulated via fp32 atomics.
__device__ __forceinline__ void gemm64_atomic(
    const unsigned short* __restrict__ A, const unsigned short* __restrict__ BT,
    float* __restrict__ C, int m0, int n0, int K, int N, int kbase, int kiters,
    unsigned short* As, unsigned short* Bs) {
    const int t = threadIdx.x;
    const int lane = t & 63, wid = t >> 6;
    const int wm = (wid & 1) * 32, wn = (wid >> 1) * 32;
    const int lr = lane & 15, lq = lane >> 4;
    const int r = t >> 3, c8 = (t & 7) * 8;

    s16x8 ra0, ra1, rb0, rb1;
#define LD64(kt)                                                           \
    ra0 = *(const s16x8*)(A  + (size_t)(m0 + r)      * K + (kt) + c8);     \
    ra1 = *(const s16x8*)(A  + (size_t)(m0 + r + 32) * K + (kt) + c8);     \
    rb0 = *(const s16x8*)(BT + (size_t)(n0 + r)      * K + (kt) + c8);     \
    rb1 = *(const s16x8*)(BT + (size_t)(n0 + r + 32) * K + (kt) + c8);

    f32x4 acc[2][2] = {};
    LD64(kbase);
    for (int it = 0; it < kiters; it++) {
        __syncthreads();
        *(s16x8*)&As[r * 72 + c8]        = ra0;
        *(s16x8*)&As[(r + 32) * 72 + c8] = ra1;
        *(s16x8*)&Bs[r * 72 + c8]        = rb0;
        *(s16x8*)&Bs[(r + 32) * 72 + c8] = rb1;
        __syncthreads();
        if (it + 1 < kiters) { LD64(kbase + (it + 1) * 64); }  // prefetch
#pragma unroll
        for (int s = 0; s < 2; s++) {
            s16x8 a0 = *(const s16x8*)&As[(wm + lr) * 72      + s * 32 + lq * 8];
            s16x8 a1 = *(const s16x8*)&As[(wm + 16 + lr) * 72 + s * 32 + lq * 8];
            s16x8 b0 = *(const s16x8*)&Bs[(wn + lr) * 72      + s * 32 + lq * 8];
            s16x8 b1 = *(const s16x8*)&Bs[(wn + 16 + lr) * 72 + s * 32 + lq * 8];
            acc[0][0] = __builtin_amdgcn_mfma_f32_16x16x32_bf16(a0, b0, acc[0][0], 0, 0, 0);
            acc[0][1] = __builtin_amdgcn_mfma_f32_16x16x32_bf16(a0, b1, acc[0][1], 0, 0, 0);
            acc[1][0] = __builtin_amdgcn_mfma_f32_16x16x32_bf16(a1, b0, acc[1][0], 0, 0, 0);
            acc[1][1] = __builtin_amdgcn_mfma_f32_16x16x32_bf16(a1, b1, acc[1][1], 0, 0, 0);
        }
    }
#undef LD64
#pragma unroll
    for (int i = 0; i < 2; i++)
#pragma unroll
        for (int j = 0; j < 2; j++) {
            const int col = n0 + wn + j * 16 + lr;      // C/D: col=lane&15
            const int row = m0 + wm + i * 16 + lq * 4;  //      row=quad*4+reg
#pragma unroll
            for (int rr = 0; rr < 4; rr++)
                unsafeAtomicAdd(&C[(size_t)(row + rr) * N + col], acc[i][j][rr]);
        }
}

// 32x64 tile, 4 waves. MODE 0: fp32+bias direct, 2: bf16+bias direct.
template <int MODE>
__device__ __forceinline__ void gemm32(
    const unsigned short* __restrict__ A, const unsigned short* __restrict__ BT,
    const float* __restrict__ bias, void* __restrict__ Cv,
    int m0, int n0, int KA, int KB, int N, int kbase, int kiters,
    unsigned short* As, unsigned short* Bs) {
    const int t = threadIdx.x;
    const int lane = t & 63, wid = t >> 6;
    const int wm = (wid & 1) * 16, wn = (wid >> 1) * 32;
    const int lr = lane & 15, lq = lane >> 4;
    const int r = t >> 3, c8 = (t & 7) * 8;

    s16x8 ra, rb0, rb1;
#define LD32(kt)                                                            \
    ra  = *(const s16x8*)(A  + (size_t)(m0 + r)      * KA + (kt) + c8);     \
    rb0 = *(const s16x8*)(BT + (size_t)(n0 + r)      * KB + (kt) + c8);     \
    rb1 = *(const s16x8*)(BT + (size_t)(n0 + r + 32) * KB + (kt) + c8);

    f32x4 acc[2] = {};
    LD32(kbase);
    for (int it = 0; it < kiters; it++) {
        __syncthreads();
        *(s16x8*)&As[r * 72 + c8]        = ra;
        *(s16x8*)&Bs[r * 72 + c8]        = rb0;
        *(s16x8*)&Bs[(r + 32) * 72 + c8] = rb1;
        __syncthreads();
        if (it + 1 < kiters) { LD32(kbase + (it + 1) * 64); }  // prefetch
#pragma unroll
        for (int s = 0; s < 2; s++) {
            s16x8 a0 = *(const s16x8*)&As[(wm + lr) * 72      + s * 32 + lq * 8];
            s16x8 b0 = *(const s16x8*)&Bs[(wn + lr) * 72      + s * 32 + lq * 8];
            s16x8 b1 = *(const s16x8*)&Bs[(wn + 16 + lr) * 72 + s * 32 + lq * 8];
            acc[0] = __builtin_amdgcn_mfma_f32_16x16x32_bf16(a0, b0, acc[0], 0, 0, 0);
            acc[1] = __builtin_amdgcn_mfma_f32_16x16x32_bf16(a0, b1, acc[1], 0, 0, 0);
        }
    }
#undef LD32
#pragma unroll
    for (int j = 0; j < 2; j++) {
        const int col = n0 + wn + j * 16 + lr;
        const int row = m0 + wm + lq * 4;
        const float bv = bias[col];
        if (MODE == 0) {
            float* C = (float*)Cv;
#pragma unroll
            for (int rr = 0; rr < 4; rr++)
                C[(size_t)(row + rr) * N + col] = acc[j][rr] + bv;
        } else {
            unsigned short* C = (unsigned short*)Cv;
#pragma unroll
            for (int rr = 0; rr < 4; rr++)
                C[(size_t)(row + rr) * N + col] = f2bf(acc[j][rr] + bv);
        }
    }
}

// ---------------- stage B: keys splitKx2 + qh + out_left --------------------
// [0,400): keys (64x64, splitK x2, atomics onto zeroed keys; bs cancels)
// [400,656): qh = query @ Wq + bq -> bf16
// [656,912): out = query @ WoTop + bo -> fp32 direct
__global__ __launch_bounds__(256) void k_stageB(
    const unsigned short* __restrict__ qbf, const unsigned short* __restrict__ abf,
    const unsigned short* __restrict__ WqT, const unsigned short* __restrict__ WsT,
    const unsigned short* __restrict__ WoT, const float* __restrict__ bq,
    const float* __restrict__ bo, unsigned short* __restrict__ qh,
    float* __restrict__ keys, float* __restrict__ out) {
    __shared__ __align__(16) unsigned short As[64 * 72];
    __shared__ __align__(16) unsigned short Bs[64 * 72];
    const int bid = blockIdx.x;
    if (bid < 400) {
        const int c = bid / 200, rem = bid % 200;
        const int mt = rem >> 3, nt = rem & 7;
        gemm64_atomic(abf, WsT, keys, mt * 64, nt * 64, 2048, 512,
                      c * 1024, 16, As, Bs);
    } else if (bid < 656) {
        const int r = bid - 400;
        const int mt = r >> 3, nt = r & 7;
        gemm32<2>(qbf, WqT, bq, qh, mt * 32, nt * 64, 512, 512, 512,
                  0, 8, As, Bs);
    } else {
        const int r = bid - 656;
        const int mt = r >> 3, nt = r & 7;
        gemm32<0>(qbf, WoT, bo, out, mt * 32, nt * 64, 512, 1024, 512,
                  0, 8, As, Bs);
    }
}

// ---------------- sc = qh @ keys^T per batch (MFMA, direct store) -----------
// sc[b*128+l][n], n in [0,256): cols 0..99 = qs/32, cols 128..227 = -qt/32.
__global__ __launch_bounds__(256) void k_scgemm(
    const unsigned short* __restrict__ qh, const float* __restrict__ keys,
    float* __restrict__ sc) {
    __shared__ __align__(16) unsigned short As[32 * 72];
    __shared__ __align__(16) unsigned short Bs[64 * 72];
    const int bid = blockIdx.x;
    const int mt = bid >> 2, nt = bid & 3;
    const int m0 = mt * 32, b = mt >> 2, n0 = nt * 64;
    const int t = threadIdx.x;
    const int lane = t & 63, wid = t >> 6;
    const int wm = (wid & 1) * 16, wn = (wid >> 1) * 32;
    const int lr = lane & 15, lq = lane >> 4;
    const int r = t >> 3, c8 = (t & 7) * 8;

    const int nA = n0 + r, nB = n0 + r + 32;
    int kr0 = (nA < 128) ? (b * 100 + nA) : (800 + b * 100 + (nA - 128));
    int kr1 = (nB < 128) ? (b * 100 + nB) : (800 + b * 100 + (nB - 128));
    kr0 = kr0 > 1599 ? 1599 : kr0;
    kr1 = kr1 > 1599 ? 1599 : kr1;

    s16x8 ra, rb0, rb1;
#define LDSC(kt)                                                    \
    ra  = *(const s16x8*)(qh + (size_t)(m0 + r) * 512 + (kt) + c8); \
    rb0 = cvt8(keys + (size_t)kr0 * 512 + (kt) + c8);               \
    rb1 = cvt8(keys + (size_t)kr1 * 512 + (kt) + c8);

    f32x4 acc[2] = {};
    LDSC(0);
    for (int it = 0; it < 8; it++) {
        __syncthreads();
        *(s16x8*)&As[r * 72 + c8]        = ra;
        *(s16x8*)&Bs[r * 72 + c8]        = rb0;
        *(s16x8*)&Bs[(r + 32) * 72 + c8] = rb1;
        __syncthreads();
        if (it < 7) { LDSC((it + 1) * 64); }
#pragma unroll
        for (int s = 0; s < 2; s++) {
            s16x8 a0 = *(const s16x8*)&As[(wm + lr) * 72      + s * 32 + lq * 8];
            s16x8 b0 = *(const s16x8*)&Bs[(wn + lr) * 72      + s * 32 + lq * 8];
            s16x8 b1 = *(const s16x8*)&Bs[(wn + 16 + lr) * 72 + s * 32 + lq * 8];
            acc[0] = __builtin_amdgcn_mfma_f32_16x16x32_bf16(a0, b0, acc[0], 0, 0, 0);
            acc[1] = __builtin_amdgcn_mfma_f32_16x16x32_bf16(a0, b1, acc[1], 0, 0, 0);
        }
    }
#undef LDSC
#pragma unroll
    for (int j = 0; j < 2; j++) {
        const int col = n0 + wn + j * 16 + lr;
        const int row = m0 + wm + lq * 4;
        const float scale = (col >= 128) ? -(1.0f / 32.0f) : (1.0f / 32.0f);
#pragma unroll
        for (int rr = 0; rr < 4; rr++)
            sc[(size_t)(row + rr) * 256 + col] = acc[j][rr] * scale;
    }
}

// ---------------- ctxout: softmax + ctx GEMM + out-right update -------------
// grid (16 n-tiles, 8 b, 4 l-tiles) = 512 blocks of 32(l) x 32(n), K=200.
// Tail: ctx tile -> LDS bf16 -> 16 MFMAs (K=32) vs wot slice -> atomicAdd out.
__global__ __launch_bounds__(256) void k_ctxout(
    const float* __restrict__ sc, const float* __restrict__ keys,
    const unsigned short* __restrict__ wot, float* __restrict__ out) {
    __shared__ float wbuf[200 * 33];         // [st][l], pad 33
    __shared__ float Bs[40 * 32];            // [k][n]
    __shared__ unsigned short ctxb[32 * 40]; // [l][n] bf16, stride 40

    const int t = threadIdx.x;
    const int b = blockIdx.y;
    const int n0 = blockIdx.x * 32;
    const int l0 = blockIdx.z * 32;
    const int wave = t >> 6, lane = t & 63;

    // ---- softmax: each wave handles 8 rows; lane covers cols lane*4..+3 ----
    for (int i = 0; i < 8; i++) {
        const int li = wave * 8 + i;                  // 0..31
        const float4 v = *(const float4*)(
            sc + (size_t)(b * 128 + l0 + li) * 256 + lane * 4);
        const float vv[4] = {v.x, v.y, v.z, v.w};
        const int c0 = lane * 4;
        float mS = -1e30f, mT = -1e30f;
#pragma unroll
        for (int j = 0; j < 4; j++) {
            const int col = c0 + j;
            if (col < 100) mS = fmaxf(mS, vv[j]);
            if (col >= 128 && col < 228) mT = fmaxf(mT, vv[j]);
        }
#pragma unroll
        for (int off = 32; off > 0; off >>= 1) {
            mS = fmaxf(mS, __shfl_xor(mS, off));
            mT = fmaxf(mT, __shfl_xor(mT, off));
        }
        float eS[4], eT[4], sS = 0.f, sT = 0.f;
#pragma unroll
        for (int j = 0; j < 4; j++) {
            const int col = c0 + j;
            eS[j] = (col < 100) ? __expf(vv[j] - mS) : 0.f;
            eT[j] = (col >= 128 && col < 228) ? __expf(vv[j] - mT) : 0.f;
            sS += eS[j]; sT += eT[j];
        }
#pragma unroll
        for (int off = 32; off > 0; off >>= 1) {
            sS += __shfl_xor(sS, off);
            sT += __shfl_xor(sT, off);
        }
        const float iS = 1.f / sS, iT = 1.f / sT;
#pragma unroll
        for (int j = 0; j < 4; j++) {
            const int col = c0 + j;
            if (col < 100) wbuf[col * 33 + li] = eS[j] * iS;
            if (col >= 128 && col < 228)
                wbuf[(100 + col - 128) * 33 + li] = eT[j] * iT;
        }
    }
    __syncthreads();

    // ---- ctx GEMM: acc[l][n] += w[st][l] * (+skey|-tkey)[st][n] ------------
    const int tx = t & 7, ty = t >> 3;   // tx: n/4, ty: l
    float rB[5];
    auto loadB = [&](int kbase) {
#pragma unroll
        for (int e = 0; e < 5; e++) {
            const int idx = t + e * 256;
            const int k = idx >> 5, j = idx & 31;
            const int kk = kbase + k;
            rB[e] = (kk < 100)
                ?  keys[(size_t)(b * 100 + kk) * 512 + n0 + j]
                : -keys[(size_t)(800 + b * 100 + (kk - 100)) * 512 + n0 + j];
        }
    };

    float acc[4] = {};
    loadB(0);
    for (int c5 = 0; c5 < 5; c5++) {
        __syncthreads();
#pragma unroll
        for (int e = 0; e < 5; e++) {
            const int idx = t + e * 256;
            Bs[idx] = rB[e];
        }
        __syncthreads();
        if (c5 < 4) loadB((c5 + 1) * 40);          // prefetch next chunk
#pragma unroll 8
        for (int k = 0; k < 40; k++) {
            const float ar = wbuf[(c5 * 40 + k) * 33 + ty];
            float br[4];
            *(float4*)br = *(const float4*)&Bs[k * 32 + tx * 4];
#pragma unroll
            for (int j = 0; j < 4; j++) acc[j] = fmaf(ar, br[j], acc[j]);
        }
    }

    // ---- ctx tile -> LDS bf16 (values / sqrt2, same rounding as R8) --------
    const float s2 = 0.70710678118654752f;
    {
        ushort4 o = make_ushort4(f2bf(acc[0] * s2), f2bf(acc[1] * s2),
                                 f2bf(acc[2] * s2), f2bf(acc[3] * s2));
        *(ushort4*)&ctxb[ty * 40 + tx * 4] = o;
    }
    __syncthreads();

    // ---- out-right: out[l][:] += ctx_tile @ WoBot[n0..n0+32][:] ------------
    // per wave: 8 n_out-tiles x 2 m-tiles, each one K=32 MFMA + 4 atomics/lane
    {
        const int lr = lane & 15, lq = lane >> 4;
        for (int nt = wave; nt < 32; nt += 4) {
            const int col = nt * 16 + lr;
            const unsigned short* wp = wot + (size_t)col * 1024 + 512 + n0 + lq * 8;
#pragma unroll
            for (int mi = 0; mi < 2; mi++) {
                s16x8 a = *(const s16x8*)&ctxb[(mi * 16 + lr) * 40 + lq * 8];
                s16x8 bf = *(const s16x8*)wp;
                f32x4 acc2 = {};
                acc2 = __builtin_amdgcn_mfma_f32_16x16x32_bf16(a, bf, acc2, 0, 0, 0);
                const int row = b * 128 + l0 + mi * 16 + lq * 4;
#pragma unroll
                for (int rr = 0; rr < 4; rr++)
                    unsafeAtomicAdd(&out[(size_t)(row + rr) * 512 + col], acc2[rr]);
            }
        }
    }
}

// ---------------- launch ----------------------------------------------------

extern "C" void kernel_launch(void* const* d_in, const int* in_sizes, int n_in,
                              void* d_out, int out_size, void* d_ws, size_t ws_size,
                              hipStream_t stream) {
    const float* query = (const float*)d_in[0];
    const float* src   = (const float*)d_in[1];
    const float* trg   = (const float*)d_in[2];
    const float* Wq    = (const float*)d_in[3];
    const float* bq    = (const float*)d_in[4];
    const float* Ws    = (const float*)d_in[5];
    const float* Wo    = (const float*)d_in[7];
    const float* bo    = (const float*)d_in[8];
    float* out = (float*)d_out;

    float* keys = (float*)d_ws;               // 1600*512 fp32 (unbiased)
    float* sc   = keys + 819200;              // 1024*256
    unsigned short* qbf = (unsigned short*)(sc + 262144);  // 1024x512
    unsigned short* qh  = qbf + 524288;       // 1024x512
    unsigned short* abf = qh  + 524288;       // [src;trg] 1600x2048
    unsigned short* wqt = abf + 3276800;      // WqT 512x512
    unsigned short* wst = wqt + 262144;       // WsT 512x2048
    unsigned short* wot = wst + 1048576;      // WoT 512x1024

    hipMemsetAsync(keys, 0, 819200 * sizeof(float), stream);
    k_prep<<<5504, 256, 0, stream>>>(query, src, trg, Wq, Ws, Wo,
                                     qbf, abf, wqt, wst, wot);
    k_stageB<<<912, 256, 0, stream>>>(qbf, abf, wqt, wst, wot, bq, bo,
                                      qh, keys, out);
    k_scgemm<<<128, 256, 0, stream>>>(qh, keys, sc);
    k_ctxout<<<dim3(16, 8, 4), 256, 0, stream>>>(sc, keys, wot, out);
}

// Round 11
// 134.080 us; speedup vs baseline: 1.5293x; 1.1306x over previous
//
#include <hip/hip_runtime.h>
#include <math.h>

// DynamicAttention1 — round 11: R8 base (best: 132.6us) + cast-in-staging.
// R10 lesson (3rd fusion failure): folding dependent GEMMs into consumer
// blocks serializes + concentrates atomics -> regression. Keep R8's 5-kernel
// shape; instead cut traffic and prep size:
//   * all GEMM A-operands read ORIGINAL fp32 tensors, cvt8 to bf16 in the
//     staging registers (pattern proven by scgemm's keys staging)
//   * abf/qbf buffers gone (~14MB traffic); prep = transposes + keys bias
//     init only (6304 -> 2592 blocks)
//   * ctx buffer is its own 1024x512 bf16 array; k_out B = wot+512 pre-offset
// Pipeline: prep -> stageB(keys x2 + qh + out_left) -> scgemm -> ctx -> out

typedef __attribute__((ext_vector_type(8))) short s16x8;
typedef __attribute__((ext_vector_type(4))) float f32x4;

__device__ __forceinline__ unsigned short f2bf(float f) {
    unsigned int u = __float_as_uint(f);
    return (unsigned short)((u + 0x7fffu + ((u >> 16) & 1u)) >> 16);  // RNE
}

__device__ __forceinline__ s16x8 cvt8(const float* p) {
    float4 u = *(const float4*)p, w = *(const float4*)(p + 4);
    s16x8 o;
    o[0] = (short)f2bf(u.x); o[1] = (short)f2bf(u.y);
    o[2] = (short)f2bf(u.z); o[3] = (short)f2bf(u.w);
    o[4] = (short)f2bf(w.x); o[5] = (short)f2bf(w.y);
    o[6] = (short)f2bf(w.z); o[7] = (short)f2bf(w.w);
    return o;
}

// ---------------- prep: weight transposes + keys bias init ------------------
__global__ __launch_bounds__(256) void k_prep(
    const float* __restrict__ Wq, const float* __restrict__ Ws,
    const float* __restrict__ Wo, const float* __restrict__ bs,
    unsigned short* __restrict__ WqT, unsigned short* __restrict__ WsT,
    unsigned short* __restrict__ WoT, float* __restrict__ keys) {
    __shared__ float tile[32][33];
    const int bid = blockIdx.x, t = threadIdx.x;

    if (bid < 1792) {                       // weight transpose-cast, 32x32 tiles
        const int id = bid;
        const float* W; unsigned short* O; int K, tk, tn;
        if (id < 256)       { W = Wq; O = WqT; K = 512;  tk = id >> 4;          tn = id & 15; }
        else if (id < 1280) { W = Ws; O = WsT; K = 2048; tk = (id - 256) >> 4;  tn = (id - 256) & 15; }
        else                { W = Wo; O = WoT; K = 1024; tk = (id - 1280) >> 4; tn = (id - 1280) & 15; }
        const int row = t >> 3, c4 = (t & 7) * 4;
        float4 v = *(const float4*)(W + (size_t)(tk * 32 + row) * 512 + tn * 32 + c4);
        tile[row][c4 + 0] = v.x; tile[row][c4 + 1] = v.y;
        tile[row][c4 + 2] = v.z; tile[row][c4 + 3] = v.w;
        __syncthreads();
        ushort4 o = make_ushort4(f2bf(tile[c4 + 0][row]), f2bf(tile[c4 + 1][row]),
                                 f2bf(tile[c4 + 2][row]), f2bf(tile[c4 + 3][row]));
        *(ushort4*)(O + (size_t)(tn * 32 + row) * K + tk * 32 + c4) = o;
    } else {                                // keys = broadcast bs (split-K base)
        const int f = ((bid - 1792) * 256 + t) * 4;
        *(float4*)(keys + f) = *(const float4*)(bs + (f & 511));
    }
}

// ---------------- keys GEMM: A = [src;trg] fp32 (cvt in staging) ------------
// 64x64 tile, 4 waves 2x2; split-K x2, atomics onto bias-inited keys.
__device__ __forceinline__ void gemm64_keys(
    const float* __restrict__ src, const float* __restrict__ trg,
    const unsigned short* __restrict__ BT, float* __restrict__ C,
    int m0, int n0, int kbase, unsigned short* As, unsigned short* Bs) {
    const int t = threadIdx.x;
    const int lane = t & 63, wid = t >> 6;
    const int wm = (wid & 1) * 32, wn = (wid >> 1) * 32;
    const int lr = lane & 15, lq = lane >> 4;
    const int r = t >> 3, c8 = (t & 7) * 8;

    const int ra_row = m0 + r, rb_row = m0 + r + 32;
    const float* arp = (ra_row < 800) ? (src + (size_t)ra_row * 2048)
                                      : (trg + (size_t)(ra_row - 800) * 2048);
    const float* brp = (rb_row < 800) ? (src + (size_t)rb_row * 2048)
                                      : (trg + (size_t)(rb_row - 800) * 2048);

    s16x8 ra0, ra1, rb0, rb1;
#define LDK(kt)                                                            \
    ra0 = cvt8(arp + (kt) + c8);                                           \
    ra1 = cvt8(brp + (kt) + c8);                                           \
    rb0 = *(const s16x8*)(BT + (size_t)(n0 + r)      * 2048 + (kt) + c8);  \
    rb1 = *(const s16x8*)(BT + (size_t)(n0 + r + 32) * 2048 + (kt) + c8);

    f32x4 acc[2][2] = {};
    LDK(kbase);
    for (int it = 0; it < 16; it++) {
        __syncthreads();
        *(s16x8*)&As[r * 72 + c8]        = ra0;
        *(s16x8*)&As[(r + 32) * 72 + c8] = ra1;
        *(s16x8*)&Bs[r * 72 + c8]        = rb0;
        *(s16x8*)&Bs[(r + 32) * 72 + c8] = rb1;
        __syncthreads();
        if (it < 15) { LDK(kbase + (it + 1) * 64); }  // prefetch
#pragma unroll
        for (int s = 0; s < 2; s++) {
            s16x8 a0 = *(const s16x8*)&As[(wm + lr) * 72      + s * 32 + lq * 8];
            s16x8 a1 = *(const s16x8*)&As[(wm + 16 + lr) * 72 + s * 32 + lq * 8];
            s16x8 b0 = *(const s16x8*)&Bs[(wn + lr) * 72      + s * 32 + lq * 8];
            s16x8 b1 = *(const s16x8*)&Bs[(wn + 16 + lr) * 72 + s * 32 + lq * 8];
            acc[0][0] = __builtin_amdgcn_mfma_f32_16x16x32_bf16(a0, b0, acc[0][0], 0, 0, 0);
            acc[0][1] = __builtin_amdgcn_mfma_f32_16x16x32_bf16(a0, b1, acc[0][1], 0, 0, 0);
            acc[1][0] = __builtin_amdgcn_mfma_f32_16x16x32_bf16(a1, b0, acc[1][0], 0, 0, 0);
            acc[1][1] = __builtin_amdgcn_mfma_f32_16x16x32_bf16(a1, b1, acc[1][1], 0, 0, 0);
        }
    }
#undef LDK
#pragma unroll
    for (int i = 0; i < 2; i++)
#pragma unroll
        for (int j = 0; j < 2; j++) {
            const int col = n0 + wn + j * 16 + lr;      // C/D: col=lane&15
            const int row = m0 + wm + i * 16 + lq * 4;  //      row=quad*4+reg
#pragma unroll
            for (int rr = 0; rr < 4; rr++)
                unsafeAtomicAdd(&C[(size_t)(row + rr) * 512 + col], acc[i][j][rr]);
        }
}

// 32x64 tile, 4 waves. A fp32 (cvt) or bf16. MODE 0: fp32+bias, 1: atomic,
// 2: bf16+bias. AF32: A element type fp32 if true.
template <int MODE, bool AF32>
__device__ __forceinline__ void gemm32(
    const void* __restrict__ Av, const unsigned short* __restrict__ BT,
    const float* __restrict__ bias, void* __restrict__ Cv,
    int m0, int n0, int KA, int KB, int N, int kbase, int kiters,
    unsigned short* As, unsigned short* Bs) {
    const int t = threadIdx.x;
    const int lane = t & 63, wid = t >> 6;
    const int wm = (wid & 1) * 16, wn = (wid >> 1) * 32;
    const int lr = lane & 15, lq = lane >> 4;
    const int r = t >> 3, c8 = (t & 7) * 8;
    const float* Af = (const float*)Av;
    const unsigned short* Ab = (const unsigned short*)Av;

    s16x8 ra, rb0, rb1;
#define LD32(kt)                                                                 \
    ra  = AF32 ? cvt8(Af + (size_t)(m0 + r) * KA + (kt) + c8)                    \
               : *(const s16x8*)(Ab + (size_t)(m0 + r) * KA + (kt) + c8);        \
    rb0 = *(const s16x8*)(BT + (size_t)(n0 + r)      * KB + (kt) + c8);          \
    rb1 = *(const s16x8*)(BT + (size_t)(n0 + r + 32) * KB + (kt) + c8);

    f32x4 acc[2] = {};
    LD32(kbase);
    for (int it = 0; it < kiters; it++) {
        __syncthreads();
        *(s16x8*)&As[r * 72 + c8]        = ra;
        *(s16x8*)&Bs[r * 72 + c8]        = rb0;
        *(s16x8*)&Bs[(r + 32) * 72 + c8] = rb1;
        __syncthreads();
        if (it + 1 < kiters) { LD32(kbase + (it + 1) * 64); }  // prefetch
#pragma unroll
        for (int s = 0; s < 2; s++) {
            s16x8 a0 = *(const s16x8*)&As[(wm + lr) * 72      + s * 32 + lq * 8];
            s16x8 b0 = *(const s16x8*)&Bs[(wn + lr) * 72      + s * 32 + lq * 8];
            s16x8 b1 = *(const s16x8*)&Bs[(wn + 16 + lr) * 72 + s * 32 + lq * 8];
            acc[0] = __builtin_amdgcn_mfma_f32_16x16x32_bf16(a0, b0, acc[0], 0, 0, 0);
            acc[1] = __builtin_amdgcn_mfma_f32_16x16x32_bf16(a0, b1, acc[1], 0, 0, 0);
        }
    }
#undef LD32
#pragma unroll
    for (int j = 0; j < 2; j++) {
        const int col = n0 + wn + j * 16 + lr;
        const int row = m0 + wm + lq * 4;
        if (MODE == 1) {
            float* C = (float*)Cv;
#pragma unroll
            for (int rr = 0; rr < 4; rr++)
                unsafeAtomicAdd(&C[(size_t)(row + rr) * N + col], acc[j][rr]);
        } else if (MODE == 0) {
            float* C = (float*)Cv;
            const float bv = bias[col];
#pragma unroll
            for (int rr = 0; rr < 4; rr++)
                C[(size_t)(row + rr) * N + col] = acc[j][rr] + bv;
        } else {
            unsigned short* C = (unsigned short*)Cv;
            const float bv = bias[col];
#pragma unroll
            for (int rr = 0; rr < 4; rr++)
                C[(size_t)(row + rr) * N + col] = f2bf(acc[j][rr] + bv);
        }
    }
}

// ---------------- stage B: keys splitKx2 + qh + out_left --------------------
// [0,400): keys (A = src/trg fp32 cvt-in-staging, atomics onto bias base)
// [400,656): qh = query @ Wq + bq -> bf16   (A = query fp32)
// [656,912): out = query @ WoTop + bo -> fp32 direct
__global__ __launch_bounds__(256) void k_stageB(
    const float* __restrict__ query, const float* __restrict__ src,
    const float* __restrict__ trg, const unsigned short* __restrict__ WqT,
    const unsigned short* __restrict__ WsT, const unsigned short* __restrict__ WoT,
    const float* __restrict__ bq, const float* __restrict__ bo,
    unsigned short* __restrict__ qh, float* __restrict__ keys,
    float* __restrict__ out) {
    __shared__ __align__(16) unsigned short As[64 * 72];
    __shared__ __align__(16) unsigned short Bs[64 * 72];
    const int bid = blockIdx.x;
    if (bid < 400) {
        const int c = bid / 200, rem = bid % 200;
        const int mt = rem >> 3, nt = rem & 7;
        gemm64_keys(src, trg, WsT, keys, mt * 64, nt * 64, c * 1024, As, Bs);
    } else if (bid < 656) {
        const int r = bid - 400;
        const int mt = r >> 3, nt = r & 7;
        gemm32<2, true>(query, WqT, bq, qh, mt * 32, nt * 64, 512, 512, 512,
                        0, 8, As, Bs);
    } else {
        const int r = bid - 656;
        const int mt = r >> 3, nt = r & 7;
        gemm32<0, true>(query, WoT, bo, out, mt * 32, nt * 64, 512, 1024, 512,
                        0, 8, As, Bs);
    }
}

// ---------------- sc = qh @ keys^T per batch (MFMA, direct store) -----------
// sc[b*128+l][n], n in [0,256): cols 0..99 = qs/32, cols 128..227 = -qt/32.
__global__ __launch_bounds__(256) void k_scgemm(
    const unsigned short* __restrict__ qh, const float* __restrict__ keys,
    float* __restrict__ sc) {
    __shared__ __align__(16) unsigned short As[32 * 72];
    __shared__ __align__(16) unsigned short Bs[64 * 72];
    const int bid = blockIdx.x;
    const int mt = bid >> 2, nt = bid & 3;
    const int m0 = mt * 32, b = mt >> 2, n0 = nt * 64;
    const int t = threadIdx.x;
    const int lane = t & 63, wid = t >> 6;
    const int wm = (wid & 1) * 16, wn = (wid >> 1) * 32;
    const int lr = lane & 15, lq = lane >> 4;
    const int r = t >> 3, c8 = (t & 7) * 8;

    const int nA = n0 + r, nB = n0 + r + 32;
    int kr0 = (nA < 128) ? (b * 100 + nA) : (800 + b * 100 + (nA - 128));
    int kr1 = (nB < 128) ? (b * 100 + nB) : (800 + b * 100 + (nB - 128));
    kr0 = kr0 > 1599 ? 1599 : kr0;
    kr1 = kr1 > 1599 ? 1599 : kr1;

    s16x8 ra, rb0, rb1;
#define LDSC(kt)                                                    \
    ra  = *(const s16x8*)(qh + (size_t)(m0 + r) * 512 + (kt) + c8); \
    rb0 = cvt8(keys + (size_t)kr0 * 512 + (kt) + c8);               \
    rb1 = cvt8(keys + (size_t)kr1 * 512 + (kt) + c8);

    f32x4 acc[2] = {};
    LDSC(0);
    for (int it = 0; it < 8; it++) {
        __syncthreads();
        *(s16x8*)&As[r * 72 + c8]        = ra;
        *(s16x8*)&Bs[r * 72 + c8]        = rb0;
        *(s16x8*)&Bs[(r + 32) * 72 + c8] = rb1;
        __syncthreads();
        if (it < 7) { LDSC((it + 1) * 64); }
#pragma unroll
        for (int s = 0; s < 2; s++) {
            s16x8 a0 = *(const s16x8*)&As[(wm + lr) * 72      + s * 32 + lq * 8];
            s16x8 b0 = *(const s16x8*)&Bs[(wn + lr) * 72      + s * 32 + lq * 8];
            s16x8 b1 = *(const s16x8*)&Bs[(wn + 16 + lr) * 72 + s * 32 + lq * 8];
            acc[0] = __builtin_amdgcn_mfma_f32_16x16x32_bf16(a0, b0, acc[0], 0, 0, 0);
            acc[1] = __builtin_amdgcn_mfma_f32_16x16x32_bf16(a0, b1, acc[1], 0, 0, 0);
        }
    }
#undef LDSC
#pragma unroll
    for (int j = 0; j < 2; j++) {
        const int col = n0 + wn + j * 16 + lr;
        const int row = m0 + wm + lq * 4;
        const float scale = (col >= 128) ? -(1.0f / 32.0f) : (1.0f / 32.0f);
#pragma unroll
        for (int rr = 0; rr < 4; rr++)
            sc[(size_t)(row + rr) * 256 + col] = acc[j][rr] * scale;
    }
}

// ---------------- ctx: in-block softmax + GEMM -> bf16 ctxbf ----------------
// grid (16 n-tiles, 8 b, 4 l-tiles) = 512 blocks of 32(l) x 32(n), K=200.
__global__ __launch_bounds__(256) void k_ctx(
    const float* __restrict__ sc, const float* __restrict__ keys,
    unsigned short* __restrict__ ctxbf) {
    __shared__ float wbuf[200 * 33];     // [st][l], pad 33
    __shared__ float Bs[40 * 32];        // [k][n]

    const int t = threadIdx.x;
    const int b = blockIdx.y;
    const int n0 = blockIdx.x * 32;
    const int l0 = blockIdx.z * 32;
    const int wave = t >> 6, lane = t & 63;

    // ---- softmax: each wave handles 8 rows; lane covers cols lane*4..+3 ----
    for (int i = 0; i < 8; i++) {
        const int li = wave * 8 + i;                  // 0..31
        const float4 v = *(const float4*)(
            sc + (size_t)(b * 128 + l0 + li) * 256 + lane * 4);
        const float vv[4] = {v.x, v.y, v.z, v.w};
        const int c0 = lane * 4;
        float mS = -1e30f, mT = -1e30f;
#pragma unroll
        for (int j = 0; j < 4; j++) {
            const int col = c0 + j;
            if (col < 100) mS = fmaxf(mS, vv[j]);
            if (col >= 128 && col < 228) mT = fmaxf(mT, vv[j]);
        }
#pragma unroll
        for (int off = 32; off > 0; off >>= 1) {
            mS = fmaxf(mS, __shfl_xor(mS, off));
            mT = fmaxf(mT, __shfl_xor(mT, off));
        }
        float eS[4], eT[4], sS = 0.f, sT = 0.f;
#pragma unroll
        for (int j = 0; j < 4; j++) {
            const int col = c0 + j;
            eS[j] = (col < 100) ? __expf(vv[j] - mS) : 0.f;
            eT[j] = (col >= 128 && col < 228) ? __expf(vv[j] - mT) : 0.f;
            sS += eS[j]; sT += eT[j];
        }
#pragma unroll
        for (int off = 32; off > 0; off >>= 1) {
            sS += __shfl_xor(sS, off);
            sT += __shfl_xor(sT, off);
        }
        const float iS = 1.f / sS, iT = 1.f / sT;
#pragma unroll
        for (int j = 0; j < 4; j++) {
            const int col = c0 + j;
            if (col < 100) wbuf[col * 33 + li] = eS[j] * iS;
            if (col >= 128 && col < 228)
                wbuf[(100 + col - 128) * 33 + li] = eT[j] * iT;
        }
    }
    __syncthreads();

    // ---- GEMM: acc[l][n] += w[st][l] * (+skey|-tkey)[st][n] ----------------
    const int tx = t & 7, ty = t >> 3;   // tx: n/4, ty: l
    float rB[5];
    auto loadB = [&](int kbase) {
#pragma unroll
        for (int e = 0; e < 5; e++) {
            const int idx = t + e * 256;
            const int k = idx >> 5, j = idx & 31;
            const int kk = kbase + k;
            rB[e] = (kk < 100)
                ?  keys[(size_t)(b * 100 + kk) * 512 + n0 + j]
                : -keys[(size_t)(800 + b * 100 + (kk - 100)) * 512 + n0 + j];
        }
    };

    float acc[4] = {};
    loadB(0);
    for (int c5 = 0; c5 < 5; c5++) {
        __syncthreads();
#pragma unroll
        for (int e = 0; e < 5; e++) {
            const int idx = t + e * 256;
            Bs[idx] = rB[e];
        }
        __syncthreads();
        if (c5 < 4) loadB((c5 + 1) * 40);          // prefetch next chunk
#pragma unroll 8
        for (int k = 0; k < 40; k++) {
            const float ar = wbuf[(c5 * 40 + k) * 33 + ty];
            float br[4];
            *(float4*)br = *(const float4*)&Bs[k * 32 + tx * 4];
#pragma unroll
            for (int j = 0; j < 4; j++) acc[j] = fmaf(ar, br[j], acc[j]);
        }
    }

    const float s2 = 0.70710678118654752f;  // 1/sqrt(2)
    const int m = b * 128 + l0 + ty;
    ushort4 o = make_ushort4(f2bf(acc[0] * s2), f2bf(acc[1] * s2),
                             f2bf(acc[2] * s2), f2bf(acc[3] * s2));
    *(ushort4*)(ctxbf + (size_t)m * 512 + n0 + tx * 4) = o;
}

// ---------------- out += ctx @ WoBot (atomic onto out_left result) ----------
__global__ __launch_bounds__(256) void k_out(
    const unsigned short* __restrict__ ctxbf,
    const unsigned short* __restrict__ wotBot,   // wot + 512 (pre-offset)
    float* __restrict__ out) {
    __shared__ __align__(16) unsigned short As[64 * 72];
    __shared__ __align__(16) unsigned short Bs[64 * 72];
    const int bid = blockIdx.x;
    const int mt = bid >> 3, nt = bid & 7;
    gemm32<1, false>(ctxbf, wotBot, nullptr, out, mt * 32, nt * 64,
                     512, 1024, 512, 0, 8, As, Bs);
}

// ---------------- launch ----------------------------------------------------

extern "C" void kernel_launch(void* const* d_in, const int* in_sizes, int n_in,
                              void* d_out, int out_size, void* d_ws, size_t ws_size,
                              hipStream_t stream) {
    const float* query = (const float*)d_in[0];
    const float* src   = (const float*)d_in[1];
    const float* trg   = (const float*)d_in[2];
    const float* Wq    = (const float*)d_in[3];
    const float* bq    = (const float*)d_in[4];
    const float* Ws    = (const float*)d_in[5];
    const float* bs    = (const float*)d_in[6];
    const float* Wo    = (const float*)d_in[7];
    const float* bo    = (const float*)d_in[8];
    float* out = (float*)d_out;

    float* keys = (float*)d_ws;               // 1600*512 fp32 (bias-inited)
    float* sc   = keys + 819200;              // 1024*256
    unsigned short* qh    = (unsigned short*)(sc + 262144);  // 1024x512 bf16
    unsigned short* ctxbf = qh    + 524288;   // 1024x512 bf16
    unsigned short* wqt   = ctxbf + 524288;   // WqT 512x512
    unsigned short* wst   = wqt   + 262144;   // WsT 512x2048
    unsigned short* wot   = wst   + 1048576;  // WoT 512x1024

    k_prep<<<2592, 256, 0, stream>>>(Wq, Ws, Wo, bs, wqt, wst, wot, keys);
    k_stageB<<<912, 256, 0, stream>>>(query, src, trg, wqt, wst, wot, bq, bo,
                                      qh, keys, out);
    k_scgemm<<<128, 256, 0, stream>>>(qh, keys, sc);
    k_ctx<<<dim3(16, 8, 4), 256, 0, stream>>>(sc, keys, ctxbf);
    k_out<<<256, 256, 0, stream>>>(ctxbf, wot + 512, out);
}

// Round 12
// 129.590 us; speedup vs baseline: 1.5823x; 1.0346x over previous
//
#include <hip/hip_runtime.h>
#include <math.h>

// DynamicAttention1 — round 12: re-associate out_right to cut one stage.
// R11 neutral -> traffic/prep not on critical path; accounting says ~10us per
// dependent-launch boundary. Algebraic fix (no block-level fusion, which
// failed 3x): out_right = ctx@WoBot = (ws@P_s - wt@P_t)/sqrt2, P = keys@WoBot.
// P depends only on stageB -> compute it ALONGSIDE scgemm; final stage does
// softmax + w@P straight into out (atomics). ctxbf + k_out eliminated.
//   pipeline: prep(transposes + keys zero) -> stageB(keys x2 + qh + out_left)
//             -> stageC(scgemm 128 + Pgemm 200) -> stageD(softmax + wP -> out)
// keys stay UNBIASED everywhere: bs cancels in scores (difference) and in
// ctx (softmax weights sum to 1) — verified empirically in R9/R10.

typedef __attribute__((ext_vector_type(8))) short s16x8;
typedef __attribute__((ext_vector_type(4))) float f32x4;

__device__ __forceinline__ unsigned short f2bf(float f) {
    unsigned int u = __float_as_uint(f);
    return (unsigned short)((u + 0x7fffu + ((u >> 16) & 1u)) >> 16);  // RNE
}

__device__ __forceinline__ s16x8 cvt8(const float* p) {
    float4 u = *(const float4*)p, w = *(const float4*)(p + 4);
    s16x8 o;
    o[0] = (short)f2bf(u.x); o[1] = (short)f2bf(u.y);
    o[2] = (short)f2bf(u.z); o[3] = (short)f2bf(u.w);
    o[4] = (short)f2bf(w.x); o[5] = (short)f2bf(w.y);
    o[6] = (short)f2bf(w.z); o[7] = (short)f2bf(w.w);
    return o;
}

// ---------------- prep: weight transposes + keys zero-init ------------------
__global__ __launch_bounds__(256) void k_prep(
    const float* __restrict__ Wq, const float* __restrict__ Ws,
    const float* __restrict__ Wo,
    unsigned short* __restrict__ WqT, unsigned short* __restrict__ WsT,
    unsigned short* __restrict__ WoT, float* __restrict__ keys) {
    __shared__ float tile[32][33];
    const int bid = blockIdx.x, t = threadIdx.x;

    if (bid < 1792) {                       // weight transpose-cast, 32x32 tiles
        const int id = bid;
        const float* W; unsigned short* O; int K, tk, tn;
        if (id < 256)       { W = Wq; O = WqT; K = 512;  tk = id >> 4;          tn = id & 15; }
        else if (id < 1280) { W = Ws; O = WsT; K = 2048; tk = (id - 256) >> 4;  tn = (id - 256) & 15; }
        else                { W = Wo; O = WoT; K = 1024; tk = (id - 1280) >> 4; tn = (id - 1280) & 15; }
        const int row = t >> 3, c4 = (t & 7) * 4;
        float4 v = *(const float4*)(W + (size_t)(tk * 32 + row) * 512 + tn * 32 + c4);
        tile[row][c4 + 0] = v.x; tile[row][c4 + 1] = v.y;
        tile[row][c4 + 2] = v.z; tile[row][c4 + 3] = v.w;
        __syncthreads();
        ushort4 o = make_ushort4(f2bf(tile[c4 + 0][row]), f2bf(tile[c4 + 1][row]),
                                 f2bf(tile[c4 + 2][row]), f2bf(tile[c4 + 3][row]));
        *(ushort4*)(O + (size_t)(tn * 32 + row) * K + tk * 32 + c4) = o;
    } else {                                // keys = 0 (split-K base, unbiased)
        const int f = ((bid - 1792) * 256 + t) * 4;
        *(float4*)(keys + f) = make_float4(0.f, 0.f, 0.f, 0.f);
    }
}

// ---------------- keys GEMM: A = [src;trg] fp32 (cvt in staging) ------------
// 64x64 tile, 4 waves 2x2; split-K x2, atomics onto zeroed keys.
__device__ __forceinline__ void gemm64_keys(
    const float* __restrict__ src, const float* __restrict__ trg,
    const unsigned short* __restrict__ BT, float* __restrict__ C,
    int m0, int n0, int kbase, unsigned short* As, unsigned short* Bs) {
    const int t = threadIdx.x;
    const int lane = t & 63, wid = t >> 6;
    const int wm = (wid & 1) * 32, wn = (wid >> 1) * 32;
    const int lr = lane & 15, lq = lane >> 4;
    const int r = t >> 3, c8 = (t & 7) * 8;

    const int ra_row = m0 + r, rb_row = m0 + r + 32;
    const float* arp = (ra_row < 800) ? (src + (size_t)ra_row * 2048)
                                      : (trg + (size_t)(ra_row - 800) * 2048);
    const float* brp = (rb_row < 800) ? (src + (size_t)rb_row * 2048)
                                      : (trg + (size_t)(rb_row - 800) * 2048);

    s16x8 ra0, ra1, rb0, rb1;
#define LDK(kt)                                                            \
    ra0 = cvt8(arp + (kt) + c8);                                           \
    ra1 = cvt8(brp + (kt) + c8);                                           \
    rb0 = *(const s16x8*)(BT + (size_t)(n0 + r)      * 2048 + (kt) + c8);  \
    rb1 = *(const s16x8*)(BT + (size_t)(n0 + r + 32) * 2048 + (kt) + c8);

    f32x4 acc[2][2] = {};
    LDK(kbase);
    for (int it = 0; it < 16; it++) {
        __syncthreads();
        *(s16x8*)&As[r * 72 + c8]        = ra0;
        *(s16x8*)&As[(r + 32) * 72 + c8] = ra1;
        *(s16x8*)&Bs[r * 72 + c8]        = rb0;
        *(s16x8*)&Bs[(r + 32) * 72 + c8] = rb1;
        __syncthreads();
        if (it < 15) { LDK(kbase + (it + 1) * 64); }  // prefetch
#pragma unroll
        for (int s = 0; s < 2; s++) {
            s16x8 a0 = *(const s16x8*)&As[(wm + lr) * 72      + s * 32 + lq * 8];
            s16x8 a1 = *(const s16x8*)&As[(wm + 16 + lr) * 72 + s * 32 + lq * 8];
            s16x8 b0 = *(const s16x8*)&Bs[(wn + lr) * 72      + s * 32 + lq * 8];
            s16x8 b1 = *(const s16x8*)&Bs[(wn + 16 + lr) * 72 + s * 32 + lq * 8];
            acc[0][0] = __builtin_amdgcn_mfma_f32_16x16x32_bf16(a0, b0, acc[0][0], 0, 0, 0);
            acc[0][1] = __builtin_amdgcn_mfma_f32_16x16x32_bf16(a0, b1, acc[0][1], 0, 0, 0);
            acc[1][0] = __builtin_amdgcn_mfma_f32_16x16x32_bf16(a1, b0, acc[1][0], 0, 0, 0);
            acc[1][1] = __builtin_amdgcn_mfma_f32_16x16x32_bf16(a1, b1, acc[1][1], 0, 0, 0);
        }
    }
#undef LDK
#pragma unroll
    for (int i = 0; i < 2; i++)
#pragma unroll
        for (int j = 0; j < 2; j++) {
            const int col = n0 + wn + j * 16 + lr;      // C/D: col=lane&15
            const int row = m0 + wm + i * 16 + lq * 4;  //      row=quad*4+reg
#pragma unroll
            for (int rr = 0; rr < 4; rr++)
                unsafeAtomicAdd(&C[(size_t)(row + rr) * 512 + col], acc[i][j][rr]);
        }
}

// ---------------- P GEMM: P = keys @ WoBot (direct fp32 store) --------------
// 64x64 tile, 4 waves 2x2, K=512 (8 iters). A = keys fp32 cvt, B = wot+512.
__device__ __forceinline__ void gemm64_P(
    const float* __restrict__ keys, const unsigned short* __restrict__ wotBot,
    float* __restrict__ P, int m0, int n0, unsigned short* As,
    unsigned short* Bs) {
    const int t = threadIdx.x;
    const int lane = t & 63, wid = t >> 6;
    const int wm = (wid & 1) * 32, wn = (wid >> 1) * 32;
    const int lr = lane & 15, lq = lane >> 4;
    const int r = t >> 3, c8 = (t & 7) * 8;

    s16x8 ra0, ra1, rb0, rb1;
#define LDP(kt)                                                               \
    ra0 = cvt8(keys + (size_t)(m0 + r)      * 512 + (kt) + c8);               \
    ra1 = cvt8(keys + (size_t)(m0 + r + 32) * 512 + (kt) + c8);               \
    rb0 = *(const s16x8*)(wotBot + (size_t)(n0 + r)      * 1024 + (kt) + c8); \
    rb1 = *(const s16x8*)(wotBot + (size_t)(n0 + r + 32) * 1024 + (kt) + c8);

    f32x4 acc[2][2] = {};
    LDP(0);
    for (int it = 0; it < 8; it++) {
        __syncthreads();
        *(s16x8*)&As[r * 72 + c8]        = ra0;
        *(s16x8*)&As[(r + 32) * 72 + c8] = ra1;
        *(s16x8*)&Bs[r * 72 + c8]        = rb0;
        *(s16x8*)&Bs[(r + 32) * 72 + c8] = rb1;
        __syncthreads();
        if (it < 7) { LDP((it + 1) * 64); }  // prefetch
#pragma unroll
        for (int s = 0; s < 2; s++) {
            s16x8 a0 = *(const s16x8*)&As[(wm + lr) * 72      + s * 32 + lq * 8];
            s16x8 a1 = *(const s16x8*)&As[(wm + 16 + lr) * 72 + s * 32 + lq * 8];
            s16x8 b0 = *(const s16x8*)&Bs[(wn + lr) * 72      + s * 32 + lq * 8];
            s16x8 b1 = *(const s16x8*)&Bs[(wn + 16 + lr) * 72 + s * 32 + lq * 8];
            acc[0][0] = __builtin_amdgcn_mfma_f32_16x16x32_bf16(a0, b0, acc[0][0], 0, 0, 0);
            acc[0][1] = __builtin_amdgcn_mfma_f32_16x16x32_bf16(a0, b1, acc[0][1], 0, 0, 0);
            acc[1][0] = __builtin_amdgcn_mfma_f32_16x16x32_bf16(a1, b0, acc[1][0], 0, 0, 0);
            acc[1][1] = __builtin_amdgcn_mfma_f32_16x16x32_bf16(a1, b1, acc[1][1], 0, 0, 0);
        }
    }
#undef LDP
#pragma unroll
    for (int i = 0; i < 2; i++)
#pragma unroll
        for (int j = 0; j < 2; j++) {
            const int col = n0 + wn + j * 16 + lr;
            const int row = m0 + wm + i * 16 + lq * 4;
#pragma unroll
            for (int rr = 0; rr < 4; rr++)
                P[(size_t)(row + rr) * 512 + col] = acc[i][j][rr];
        }
}

// 32x64 tile, 4 waves. A fp32 (cvt in staging). MODE 0: fp32+bias,
// 2: bf16+bias.
template <int MODE>
__device__ __forceinline__ void gemm32(
    const float* __restrict__ A, const unsigned short* __restrict__ BT,
    const float* __restrict__ bias, void* __restrict__ Cv,
    int m0, int n0, int KA, int KB, int N, int kiters,
    unsigned short* As, unsigned short* Bs) {
    const int t = threadIdx.x;
    const int lane = t & 63, wid = t >> 6;
    const int wm = (wid & 1) * 16, wn = (wid >> 1) * 32;
    const int lr = lane & 15, lq = lane >> 4;
    const int r = t >> 3, c8 = (t & 7) * 8;

    s16x8 ra, rb0, rb1;
#define LD32(kt)                                                            \
    ra  = cvt8(A + (size_t)(m0 + r) * KA + (kt) + c8);                      \
    rb0 = *(const s16x8*)(BT + (size_t)(n0 + r)      * KB + (kt) + c8);     \
    rb1 = *(const s16x8*)(BT + (size_t)(n0 + r + 32) * KB + (kt) + c8);

    f32x4 acc[2] = {};
    LD32(0);
    for (int it = 0; it < kiters; it++) {
        __syncthreads();
        *(s16x8*)&As[r * 72 + c8]        = ra;
        *(s16x8*)&Bs[r * 72 + c8]        = rb0;
        *(s16x8*)&Bs[(r + 32) * 72 + c8] = rb1;
        __syncthreads();
        if (it + 1 < kiters) { LD32((it + 1) * 64); }  // prefetch
#pragma unroll
        for (int s = 0; s < 2; s++) {
            s16x8 a0 = *(const s16x8*)&As[(wm + lr) * 72      + s * 32 + lq * 8];
            s16x8 b0 = *(const s16x8*)&Bs[(wn + lr) * 72      + s * 32 + lq * 8];
            s16x8 b1 = *(const s16x8*)&Bs[(wn + 16 + lr) * 72 + s * 32 + lq * 8];
            acc[0] = __builtin_amdgcn_mfma_f32_16x16x32_bf16(a0, b0, acc[0], 0, 0, 0);
            acc[1] = __builtin_amdgcn_mfma_f32_16x16x32_bf16(a0, b1, acc[1], 0, 0, 0);
        }
    }
#undef LD32
#pragma unroll
    for (int j = 0; j < 2; j++) {
        const int col = n0 + wn + j * 16 + lr;
        const int row = m0 + wm + lq * 4;
        const float bv = bias[col];
        if (MODE == 0) {
            float* C = (float*)Cv;
#pragma unroll
            for (int rr = 0; rr < 4; rr++)
                C[(size_t)(row + rr) * N + col] = acc[j][rr] + bv;
        } else {
            unsigned short* C = (unsigned short*)Cv;
#pragma unroll
            for (int rr = 0; rr < 4; rr++)
                C[(size_t)(row + rr) * N + col] = f2bf(acc[j][rr] + bv);
        }
    }
}

// ---------------- stage B: keys splitKx2 + qh + out_left --------------------
__global__ __launch_bounds__(256) void k_stageB(
    const float* __restrict__ query, const float* __restrict__ src,
    const float* __restrict__ trg, const unsigned short* __restrict__ WqT,
    const unsigned short* __restrict__ WsT, const unsigned short* __restrict__ WoT,
    const float* __restrict__ bq, const float* __restrict__ bo,
    unsigned short* __restrict__ qh, float* __restrict__ keys,
    float* __restrict__ out) {
    __shared__ __align__(16) unsigned short As[64 * 72];
    __shared__ __align__(16) unsigned short Bs[64 * 72];
    const int bid = blockIdx.x;
    if (bid < 400) {
        const int c = bid / 200, rem = bid % 200;
        const int mt = rem >> 3, nt = rem & 7;
        gemm64_keys(src, trg, WsT, keys, mt * 64, nt * 64, c * 1024, As, Bs);
    } else if (bid < 656) {
        const int r = bid - 400;
        const int mt = r >> 3, nt = r & 7;
        gemm32<2>(query, WqT, bq, qh, mt * 32, nt * 64, 512, 512, 512,
                  8, As, Bs);
    } else {
        const int r = bid - 656;
        const int mt = r >> 3, nt = r & 7;
        gemm32<0>(query, WoT, bo, out, mt * 32, nt * 64, 512, 1024, 512,
                  8, As, Bs);
    }
}

// ---------------- stage C: scgemm (128 blocks) + Pgemm (200 blocks) ---------
// scgemm: sc[b*128+l][n], cols 0..99 = qs/32, cols 128..227 = -qt/32.
// Pgemm:  P = keys @ WoBot, [1600][512] fp32 direct.
__global__ __launch_bounds__(256) void k_stageC(
    const unsigned short* __restrict__ qh, const float* __restrict__ keys,
    const unsigned short* __restrict__ wotBot, float* __restrict__ sc,
    float* __restrict__ P) {
    __shared__ __align__(16) unsigned short As[64 * 72];
    __shared__ __align__(16) unsigned short Bs[64 * 72];
    const int bid = blockIdx.x;
    const int t = threadIdx.x;

    if (bid >= 128) {                       // ---- Pgemm ----
        const int rem = bid - 128;
        gemm64_P(keys, wotBot, P, (rem >> 3) * 64, (rem & 7) * 64, As, Bs);
        return;
    }

    // ---- scgemm ----
    const int mt = bid >> 2, nt = bid & 3;
    const int m0 = mt * 32, b = mt >> 2, n0 = nt * 64;
    const int lane = t & 63, wid = t >> 6;
    const int wm = (wid & 1) * 16, wn = (wid >> 1) * 32;
    const int lr = lane & 15, lq = lane >> 4;
    const int r = t >> 3, c8 = (t & 7) * 8;

    const int nA = n0 + r, nB = n0 + r + 32;
    int kr0 = (nA < 128) ? (b * 100 + nA) : (800 + b * 100 + (nA - 128));
    int kr1 = (nB < 128) ? (b * 100 + nB) : (800 + b * 100 + (nB - 128));
    kr0 = kr0 > 1599 ? 1599 : kr0;
    kr1 = kr1 > 1599 ? 1599 : kr1;

    s16x8 ra, rb0, rb1;
#define LDSC(kt)                                                    \
    ra  = *(const s16x8*)(qh + (size_t)(m0 + r) * 512 + (kt) + c8); \
    rb0 = cvt8(keys + (size_t)kr0 * 512 + (kt) + c8);               \
    rb1 = cvt8(keys + (size_t)kr1 * 512 + (kt) + c8);

    f32x4 acc[2] = {};
    LDSC(0);
    for (int it = 0; it < 8; it++) {
        __syncthreads();
        *(s16x8*)&As[r * 72 + c8]        = ra;
        *(s16x8*)&Bs[r * 72 + c8]        = rb0;
        *(s16x8*)&Bs[(r + 32) * 72 + c8] = rb1;
        __syncthreads();
        if (it < 7) { LDSC((it + 1) * 64); }
#pragma unroll
        for (int s = 0; s < 2; s++) {
            s16x8 a0 = *(const s16x8*)&As[(wm + lr) * 72      + s * 32 + lq * 8];
            s16x8 b0 = *(const s16x8*)&Bs[(wn + lr) * 72      + s * 32 + lq * 8];
            s16x8 b1 = *(const s16x8*)&Bs[(wn + 16 + lr) * 72 + s * 32 + lq * 8];
            acc[0] = __builtin_amdgcn_mfma_f32_16x16x32_bf16(a0, b0, acc[0], 0, 0, 0);
            acc[1] = __builtin_amdgcn_mfma_f32_16x16x32_bf16(a0, b1, acc[1], 0, 0, 0);
        }
    }
#undef LDSC
#pragma unroll
    for (int j = 0; j < 2; j++) {
        const int col = n0 + wn + j * 16 + lr;
        const int row = m0 + wm + lq * 4;
        const float scale = (col >= 128) ? -(1.0f / 32.0f) : (1.0f / 32.0f);
#pragma unroll
        for (int rr = 0; rr < 4; rr++)
            sc[(size_t)(row + rr) * 256 + col] = acc[j][rr] * scale;
    }
}

// ---------------- stage D: softmax + wP GEMM -> atomic into out -------------
// grid (16 n-tiles, 8 b, 4 l-tiles) = 512 blocks of 32(l) x 32(n), K=200.
// out[m][n] += (sum_s ws*P_s - sum_t wt*P_t)/sqrt2  (out has out_left+bo).
__global__ __launch_bounds__(256) void k_stageD(
    const float* __restrict__ sc, const float* __restrict__ P,
    float* __restrict__ out) {
    __shared__ float wbuf[200 * 33];     // [st][l], pad 33
    __shared__ float Bs[40 * 32];        // [k][n]

    const int t = threadIdx.x;
    const int b = blockIdx.y;
    const int n0 = blockIdx.x * 32;
    const int l0 = blockIdx.z * 32;
    const int wave = t >> 6, lane = t & 63;

    // ---- softmax: each wave handles 8 rows; lane covers cols lane*4..+3 ----
    for (int i = 0; i < 8; i++) {
        const int li = wave * 8 + i;                  // 0..31
        const float4 v = *(const float4*)(
            sc + (size_t)(b * 128 + l0 + li) * 256 + lane * 4);
        const float vv[4] = {v.x, v.y, v.z, v.w};
        const int c0 = lane * 4;
        float mS = -1e30f, mT = -1e30f;
#pragma unroll
        for (int j = 0; j < 4; j++) {
            const int col = c0 + j;
            if (col < 100) mS = fmaxf(mS, vv[j]);
            if (col >= 128 && col < 228) mT = fmaxf(mT, vv[j]);
        }
#pragma unroll
        for (int off = 32; off > 0; off >>= 1) {
            mS = fmaxf(mS, __shfl_xor(mS, off));
            mT = fmaxf(mT, __shfl_xor(mT, off));
        }
        float eS[4], eT[4], sS = 0.f, sT = 0.f;
#pragma unroll
        for (int j = 0; j < 4; j++) {
            const int col = c0 + j;
            eS[j] = (col < 100) ? __expf(vv[j] - mS) : 0.f;
            eT[j] = (col >= 128 && col < 228) ? __expf(vv[j] - mT) : 0.f;
            sS += eS[j]; sT += eT[j];
        }
#pragma unroll
        for (int off = 32; off > 0; off >>= 1) {
            sS += __shfl_xor(sS, off);
            sT += __shfl_xor(sT, off);
        }
        const float iS = 1.f / sS, iT = 1.f / sT;
#pragma unroll
        for (int j = 0; j < 4; j++) {
            const int col = c0 + j;
            if (col < 100) wbuf[col * 33 + li] = eS[j] * iS;
            if (col >= 128 && col < 228)
                wbuf[(100 + col - 128) * 33 + li] = eT[j] * iT;
        }
    }
    __syncthreads();

    // ---- GEMM: acc[l][n] += w[st][l] * (+P_s|-P_t)[st][n] ------------------
    const int tx = t & 7, ty = t >> 3;   // tx: n/4, ty: l
    float rB[5];
    auto loadB = [&](int kbase) {
#pragma unroll
        for (int e = 0; e < 5; e++) {
            const int idx = t + e * 256;
            const int k = idx >> 5, j = idx & 31;
            const int kk = kbase + k;
            rB[e] = (kk < 100)
                ?  P[(size_t)(b * 100 + kk) * 512 + n0 + j]
                : -P[(size_t)(800 + b * 100 + (kk - 100)) * 512 + n0 + j];
        }
    };

    float acc[4] = {};
    loadB(0);
    for (int c5 = 0; c5 < 5; c5++) {
        __syncthreads();
#pragma unroll
        for (int e = 0; e < 5; e++) {
            const int idx = t + e * 256;
            Bs[idx] = rB[e];
        }
        __syncthreads();
        if (c5 < 4) loadB((c5 + 1) * 40);          // prefetch next chunk
#pragma unroll 8
        for (int k = 0; k < 40; k++) {
            const float ar = wbuf[(c5 * 40 + k) * 33 + ty];
            float br[4];
            *(float4*)br = *(const float4*)&Bs[k * 32 + tx * 4];
#pragma unroll
            for (int j = 0; j < 4; j++) acc[j] = fmaf(ar, br[j], acc[j]);
        }
    }

    const float s2 = 0.70710678118654752f;  // 1/sqrt(2)
    const int m = b * 128 + l0 + ty;
#pragma unroll
    for (int j = 0; j < 4; j++)
        unsafeAtomicAdd(&out[(size_t)m * 512 + n0 + tx * 4 + j], acc[j] * s2);
}

// ---------------- launch ----------------------------------------------------

extern "C" void kernel_launch(void* const* d_in, const int* in_sizes, int n_in,
                              void* d_out, int out_size, void* d_ws, size_t ws_size,
                              hipStream_t stream) {
    const float* query = (const float*)d_in[0];
    const float* src   = (const float*)d_in[1];
    const float* trg   = (const float*)d_in[2];
    const float* Wq    = (const float*)d_in[3];
    const float* bq    = (const float*)d_in[4];
    const float* Ws    = (const float*)d_in[5];
    const float* Wo    = (const float*)d_in[7];
    const float* bo    = (const float*)d_in[8];
    float* out = (float*)d_out;

    float* keys = (float*)d_ws;               // 1600*512 fp32 (UNBIASED)
    float* sc   = keys + 819200;              // 1024*256 fp32
    float* P    = sc   + 262144;              // 1600*512 fp32 = keys @ WoBot
    unsigned short* qh  = (unsigned short*)(P + 819200);  // 1024x512 bf16
    unsigned short* wqt = qh  + 524288;       // WqT 512x512
    unsigned short* wst = wqt + 262144;       // WsT 512x2048
    unsigned short* wot = wst + 1048576;      // WoT 512x1024

    k_prep<<<2592, 256, 0, stream>>>(Wq, Ws, Wo, wqt, wst, wot, keys);
    k_stageB<<<912, 256, 0, stream>>>(query, src, trg, wqt, wst, wot, bq, bo,
                                      qh, keys, out);
    k_stageC<<<328, 256, 0, stream>>>(qh, keys, wot + 512, sc, P);
    k_stageD<<<dim3(16, 8, 4), 256, 0, stream>>>(sc, P, out);
}